// Round 1
// baseline (811.112 us; speedup 1.0000x reference)
//
#include <hip/hip_runtime.h>
#include <hip/hip_bf16.h>

typedef __bf16 bf16;
typedef __bf16 bf16x4 __attribute__((ext_vector_type(4)));
typedef __bf16 bf16x8 __attribute__((ext_vector_type(8)));
typedef float f32x4 __attribute__((ext_vector_type(4)));
typedef unsigned short ushort8 __attribute__((ext_vector_type(8)));

// ---------------- staging helpers (128 rows x 32 cols -> LDS bf16 [128][40]) ----------------
__device__ __forceinline__ void stage_tile_f32(bf16* lds, const float* g, int ldg, int tid) {
  const int col = (tid & 7) * 4;   // 0..28
  const int row = tid >> 3;        // 0..31
#pragma unroll
  for (int p = 0; p < 4; ++p) {
    const float4 v = *reinterpret_cast<const float4*>(g + (size_t)(row + p * 32) * ldg + col);
    bf16x4 w = { (bf16)v.x, (bf16)v.y, (bf16)v.z, (bf16)v.w };
    *reinterpret_cast<bf16x4*>(lds + (row + p * 32) * 40 + col) = w;
  }
}
__device__ __forceinline__ void stage_tile_b16(bf16* lds, const unsigned short* g, int ldg, int tid) {
  const int col = (tid & 3) * 8;   // 0..24
  const int row = tid >> 2;        // 0..63
#pragma unroll
  for (int p = 0; p < 2; ++p) {
    ushort8 v = *reinterpret_cast<const ushort8*>(g + (size_t)(row + p * 64) * ldg + col);
    *reinterpret_cast<ushort8*>(lds + (row + p * 64) * 40 + col) = v;
  }
}

// ---------------- NT GEMM: C[M,N] = scale * (A[M,K] . B[N,K]^T) + bias ----------------
// 128x128 tile, BK=32, 4 waves (2x2), each wave 64x64 via 4x4 mfma_f32_16x16x32_bf16.
template <typename TA, typename TB, bool OUT_BF16, bool HAS_BIAS>
__global__ __launch_bounds__(256) void gemm_nt(
    const TA* __restrict__ A, const TB* __restrict__ B,
    const float* __restrict__ bias, void* __restrict__ Cout,
    int M, int N, int K, float scale) {
  constexpr int LDT = 40;  // 32 + 8 pad (stride 80B -> conflict-free b128 reads)
  __shared__ bf16 Alds[128 * LDT];
  __shared__ bf16 Blds[128 * LDT];
  const int tid = threadIdx.x;
  const int m0 = blockIdx.x * 128, n0 = blockIdx.y * 128;
  const int lane = tid & 63, wid = tid >> 6;
  const int wr = wid >> 1, wc = wid & 1;
  const int lrow = lane & 15, lko = (lane >> 4) * 8;

  f32x4 acc[4][4] = {};

  for (int k0 = 0; k0 < K; k0 += 32) {
    if constexpr (sizeof(TA) == 4)
      stage_tile_f32(Alds, (const float*)A + (size_t)m0 * K + k0, K, tid);
    else
      stage_tile_b16(Alds, (const unsigned short*)A + (size_t)m0 * K + k0, K, tid);
    if constexpr (sizeof(TB) == 4)
      stage_tile_f32(Blds, (const float*)B + (size_t)n0 * K + k0, K, tid);
    else
      stage_tile_b16(Blds, (const unsigned short*)B + (size_t)n0 * K + k0, K, tid);
    __syncthreads();

    bf16x8 af[4], bfr[4];
#pragma unroll
    for (int i = 0; i < 4; ++i)
      af[i] = *reinterpret_cast<const bf16x8*>(&Alds[(wr * 64 + i * 16 + lrow) * LDT + lko]);
#pragma unroll
    for (int i = 0; i < 4; ++i)
      bfr[i] = *reinterpret_cast<const bf16x8*>(&Blds[(wc * 64 + i * 16 + lrow) * LDT + lko]);
#pragma unroll
    for (int mi = 0; mi < 4; ++mi)
#pragma unroll
      for (int ni = 0; ni < 4; ++ni)
        acc[mi][ni] = __builtin_amdgcn_mfma_f32_16x16x32_bf16(af[mi], bfr[ni], acc[mi][ni], 0, 0, 0);
    __syncthreads();
  }

  // epilogue: C/D layout col = lane&15, row = (lane>>4)*4 + j  [m89-verified]
  const int lro = (lane >> 4) * 4;
#pragma unroll
  for (int ni = 0; ni < 4; ++ni) {
    const int gcol = n0 + wc * 64 + ni * 16 + lrow;
    float bv = 0.f;
    if constexpr (HAS_BIAS) bv = bias[gcol];
#pragma unroll
    for (int mi = 0; mi < 4; ++mi) {
      const int grow = m0 + wr * 64 + mi * 16 + lro;
#pragma unroll
      for (int j = 0; j < 4; ++j) {
        const float c = acc[mi][ni][j] * scale + bv;
        if constexpr (OUT_BF16)
          ((bf16*)Cout)[(size_t)(grow + j) * N + gcol] = (bf16)c;
        else
          ((float*)Cout)[(size_t)(grow + j) * N + gcol] = c;
      }
    }
  }
}

// ---------------- prep: W3t[e,k] = bf16(prior[k] * dic_z[k,e]), transposed ----------------
__global__ __launch_bounds__(256) void prep_w3t(const float* __restrict__ dic,
                                                const float* __restrict__ prior,
                                                bf16* __restrict__ w3t) {
  const int KD = 4096, E = 2048;
  __shared__ bf16 t[64][72];
  const int k0 = blockIdx.x * 64, e0 = blockIdx.y * 64;
  const int tid = threadIdx.x;
  const int er = (tid & 15) * 4;  // e offset within tile
  const int kr = tid >> 4;        // 0..15
#pragma unroll
  for (int p = 0; p < 4; ++p) {
    const int k = kr + p * 16;
    const float pr = prior[k0 + k];
    const float4 v = *reinterpret_cast<const float4*>(dic + (size_t)(k0 + k) * E + e0 + er);
    t[er + 0][k] = (bf16)(v.x * pr);
    t[er + 1][k] = (bf16)(v.y * pr);
    t[er + 2][k] = (bf16)(v.z * pr);
    t[er + 3][k] = (bf16)(v.w * pr);
  }
  __syncthreads();
  const int e = tid >> 2, kc = (tid & 3) * 16;
  ushort8 a = *reinterpret_cast<ushort8*>(&t[e][kc]);
  ushort8 b = *reinterpret_cast<ushort8*>(&t[e][kc + 8]);
  unsigned short* dst = (unsigned short*)w3t + (size_t)(e0 + e) * KD + k0 + kc;
  *reinterpret_cast<ushort8*>(dst) = a;
  *reinterpret_cast<ushort8*>(dst + 8) = b;
}

// ---------------- in-place row softmax over bf16 logits [M rows x 4096] ----------------
__global__ __launch_bounds__(256) void softmax_rows(unsigned short* __restrict__ S) {
  const int K = 4096;
  unsigned short* row = S + (size_t)blockIdx.x * K;
  const int tid = threadIdx.x;
  const int lane = tid & 63, w = tid >> 6;
  __shared__ float red[8];

  ushort8 v0 = *reinterpret_cast<const ushort8*>(row + tid * 8);
  ushort8 v1 = *reinterpret_cast<const ushort8*>(row + 2048 + tid * 8);
  float x[16];
#pragma unroll
  for (int i = 0; i < 8; ++i) {
    x[i]     = __uint_as_float(((unsigned)v0[i]) << 16);
    x[8 + i] = __uint_as_float(((unsigned)v1[i]) << 16);
  }
  float mx = x[0];
#pragma unroll
  for (int i = 1; i < 16; ++i) mx = fmaxf(mx, x[i]);
#pragma unroll
  for (int o = 32; o; o >>= 1) mx = fmaxf(mx, __shfl_xor(mx, o));
  if (lane == 0) red[w] = mx;
  __syncthreads();
  mx = fmaxf(fmaxf(red[0], red[1]), fmaxf(red[2], red[3]));

  float s = 0.f;
#pragma unroll
  for (int i = 0; i < 16; ++i) { x[i] = __expf(x[i] - mx); s += x[i]; }
#pragma unroll
  for (int o = 32; o; o >>= 1) s += __shfl_xor(s, o);
  if (lane == 0) red[4 + w] = s;
  __syncthreads();
  const float inv = 1.f / (red[4] + red[5] + red[6] + red[7]);

  ushort8 o0, o1;
#pragma unroll
  for (int i = 0; i < 8; ++i) {
    bf16 b0 = (bf16)(x[i] * inv);
    bf16 b1 = (bf16)(x[8 + i] * inv);
    o0[i] = __builtin_bit_cast(unsigned short, b0);
    o1[i] = __builtin_bit_cast(unsigned short, b1);
  }
  *reinterpret_cast<ushort8*>(row + tid * 8) = o0;
  *reinterpret_cast<ushort8*>(row + 2048 + tid * 8) = o1;
}

extern "C" void kernel_launch(void* const* d_in, const int* in_sizes, int n_in,
                              void* d_out, int out_size, void* d_ws, size_t ws_size,
                              hipStream_t stream) {
  const float* y     = (const float*)d_in[0];  // [16384,1024]
  const float* Wy_w  = (const float*)d_in[1];  // [1024,1024]
  const float* Wy_b  = (const float*)d_in[2];  // [1024]
  const float* Wz_w  = (const float*)d_in[3];  // [1024,2048]
  const float* Wz_b  = (const float*)d_in[4];  // [1024]
  const float* dic   = (const float*)d_in[5];  // [4096,2048]
  const float* prior = (const float*)d_in[6];  // [4096]
  float* z = (float*)d_out;                    // [16384,2048]

  const int M = 16384, D = 1024, E = 2048, KD = 4096;

  // workspace layout (184 MiB total)
  char* ws = (char*)d_ws;
  bf16* w3t = (bf16*)(ws);                        // 2048*4096*2 = 16 MiB
  bf16* h   = (bf16*)(ws + ((size_t)16 << 20));   // 16384*1024*2 = 32 MiB
  bf16* dzb = (bf16*)(ws + ((size_t)48 << 20));   // 4096*1024*2  =  8 MiB
  bf16* S   = (bf16*)(ws + ((size_t)56 << 20));   // 16384*4096*2 = 128 MiB

  // 1) W3t[e,k] = prior[k] * dic_z[k,e]  (bf16, transposed)
  prep_w3t<<<dim3(KD / 64, E / 64), 256, 0, stream>>>(dic, prior, w3t);
  // 2) h = y . Wy^T + Wy_b   -> bf16 [16384,1024]
  gemm_nt<float, float, true, true><<<dim3(M / 128, D / 128), 256, 0, stream>>>(
      y, Wy_w, Wy_b, h, M, D, D, 1.0f);
  // 3) dz = dic . Wz^T + Wz_b -> bf16 [4096,1024]
  gemm_nt<float, float, true, true><<<dim3(KD / 128, D / 128), 256, 0, stream>>>(
      dic, Wz_w, Wz_b, dzb, KD, D, E, 1.0f);
  // 4) S = (h . dz^T) / 32    -> bf16 [16384,4096]
  gemm_nt<unsigned short, unsigned short, true, false><<<dim3(M / 128, KD / 128), 256, 0, stream>>>(
      (const unsigned short*)h, (const unsigned short*)dzb, nullptr, S, M, KD, D, 0.03125f);
  // 5) row softmax in place
  softmax_rows<<<M, 256, 0, stream>>>((unsigned short*)S);
  // 6) z = att . W3t^T        -> f32 [16384,2048]
  gemm_nt<unsigned short, unsigned short, false, false><<<dim3(M / 128, E / 128), 256, 0, stream>>>(
      (const unsigned short*)S, (const unsigned short*)w3t, nullptr, z, M, E, KD, 1.0f);
}

// Round 2
// 734.770 us; speedup vs baseline: 1.1039x; 1.1039x over previous
//
#include <hip/hip_runtime.h>
#include <hip/hip_bf16.h>
#include <stdint.h>

typedef __bf16 bf16;
typedef __bf16 bf16x4 __attribute__((ext_vector_type(4)));
typedef __bf16 bf16x8 __attribute__((ext_vector_type(8)));
typedef float f32x4 __attribute__((ext_vector_type(4)));
typedef unsigned short ushort8 __attribute__((ext_vector_type(8)));

// ---- async global->LDS, 16B per lane. LDS dest must be wave-uniform base; HW adds lane*16.
__device__ __forceinline__ void gload16(const bf16* g, bf16* l) {
  __builtin_amdgcn_global_load_lds(
      reinterpret_cast<const __attribute__((address_space(1))) unsigned int*>(
          reinterpret_cast<uintptr_t>(g)),
      reinterpret_cast<__attribute__((address_space(3))) unsigned int*>(
          reinterpret_cast<uintptr_t>(l)),
      16, 0, 0);
}

// ---- f32 -> bf16 cast, 8 elems/thread, grid-stride ----
__global__ __launch_bounds__(256) void cast_bf16(const float* __restrict__ in,
                                                 bf16* __restrict__ out, int n8) {
  int i = blockIdx.x * blockDim.x + threadIdx.x;
  const int stride = gridDim.x * blockDim.x;
  for (; i < n8; i += stride) {
    const float4 v0 = reinterpret_cast<const float4*>(in)[i * 2];
    const float4 v1 = reinterpret_cast<const float4*>(in)[i * 2 + 1];
    bf16x8 o = { (bf16)v0.x, (bf16)v0.y, (bf16)v0.z, (bf16)v0.w,
                 (bf16)v1.x, (bf16)v1.y, (bf16)v1.z, (bf16)v1.w };
    reinterpret_cast<bf16x8*>(out)[i] = o;
  }
}

// ---------------- NT GEMM (m97 structure): C[M,N] = scale*(A[M,K].B[N,K]^T)+bias ----------------
// 128x128 tile, BK=32, 4 waves (2x2), global_load_lds w16 staging, linear LDS [128][32].
template <bool OUT_BF16, bool HAS_BIAS>
__global__ __launch_bounds__(256) void gemm_nt_bf16(
    const bf16* __restrict__ A, const bf16* __restrict__ B,
    const float* __restrict__ bias, void* __restrict__ Cout,
    int M, int N, int K, float scale) {
  __shared__ bf16 Al[128 * 32];
  __shared__ bf16 Bl[128 * 32];
  const int tid = threadIdx.x;
  const int lane = tid & 63, w = tid >> 6;
  const int m0 = blockIdx.x * 128, n0 = blockIdx.y * 128;

  // staging: tile = 8 chunks of 1KB (16 rows x 64B); wave w owns chunks 2w, 2w+1
  const int srow = w * 32 + (lane >> 2);      // rows w*32 .. w*32+15  (chunk i=0)
  const int scol = (lane & 3) * 8;            // 4 lanes x 16B per 64B row
  const bf16* ag0 = A + (size_t)(m0 + srow) * K + scol;
  const bf16* ag1 = A + (size_t)(m0 + srow + 16) * K + scol;
  const bf16* bg0 = B + (size_t)(n0 + srow) * K + scol;
  const bf16* bg1 = B + (size_t)(n0 + srow + 16) * K + scol;
  bf16* al0 = Al + (w * 2 + 0) * 512;
  bf16* al1 = Al + (w * 2 + 1) * 512;
  bf16* bl0 = Bl + (w * 2 + 0) * 512;
  bf16* bl1 = Bl + (w * 2 + 1) * 512;

  // fragment read offsets (elements); wave (wr,wc) computes 64x64
  const int wr = w >> 1, wc = w & 1;
  const int fr = lane & 15, fko = (lane >> 4) * 8;
  int aoff[4], boff[4];
#pragma unroll
  for (int i = 0; i < 4; ++i) {
    aoff[i] = (wr * 64 + i * 16 + fr) * 32 + fko;
    boff[i] = (wc * 64 + i * 16 + fr) * 32 + fko;
  }

  f32x4 acc[4][4] = {};

  for (int k0 = 0; k0 < K; k0 += 32) {
    gload16(ag0 + k0, al0);
    gload16(ag1 + k0, al1);
    gload16(bg0 + k0, bl0);
    gload16(bg1 + k0, bl1);
    __syncthreads();  // compiler drains vmcnt before barrier -> LDS tile ready

    bf16x8 af[4], bv[4];
#pragma unroll
    for (int i = 0; i < 4; ++i) af[i] = *reinterpret_cast<const bf16x8*>(Al + aoff[i]);
#pragma unroll
    for (int i = 0; i < 4; ++i) bv[i] = *reinterpret_cast<const bf16x8*>(Bl + boff[i]);
#pragma unroll
    for (int mi = 0; mi < 4; ++mi)
#pragma unroll
      for (int ni = 0; ni < 4; ++ni)
        acc[mi][ni] = __builtin_amdgcn_mfma_f32_16x16x32_bf16(af[mi], bv[ni], acc[mi][ni], 0, 0, 0);
    __syncthreads();
  }

  // epilogue: C/D layout col = lane&15, row = (lane>>4)*4 + j  [m89-verified]
  const int lro = (lane >> 4) * 4;
#pragma unroll
  for (int ni = 0; ni < 4; ++ni) {
    const int gcol = n0 + wc * 64 + ni * 16 + fr;
    float bvs = 0.f;
    if constexpr (HAS_BIAS) bvs = bias[gcol];
#pragma unroll
    for (int mi = 0; mi < 4; ++mi) {
      const int grow = m0 + wr * 64 + mi * 16 + lro;
#pragma unroll
      for (int j = 0; j < 4; ++j) {
        const float c = acc[mi][ni][j] * scale + bvs;
        if constexpr (OUT_BF16)
          ((bf16*)Cout)[(size_t)(grow + j) * N + gcol] = (bf16)c;
        else
          ((float*)Cout)[(size_t)(grow + j) * N + gcol] = c;
      }
    }
  }
}

// ---------------- prep: W3t[e,k] = bf16(prior[k] * dic_z[k,e]), transposed ----------------
__global__ __launch_bounds__(256) void prep_w3t(const float* __restrict__ dic,
                                                const float* __restrict__ prior,
                                                bf16* __restrict__ w3t) {
  const int KD = 4096, E = 2048;
  __shared__ bf16 t[64][72];
  const int k0 = blockIdx.x * 64, e0 = blockIdx.y * 64;
  const int tid = threadIdx.x;
  const int er = (tid & 15) * 4;
  const int kr = tid >> 4;
#pragma unroll
  for (int p = 0; p < 4; ++p) {
    const int k = kr + p * 16;
    const float pr = prior[k0 + k];
    const float4 v = *reinterpret_cast<const float4*>(dic + (size_t)(k0 + k) * E + e0 + er);
    t[er + 0][k] = (bf16)(v.x * pr);
    t[er + 1][k] = (bf16)(v.y * pr);
    t[er + 2][k] = (bf16)(v.z * pr);
    t[er + 3][k] = (bf16)(v.w * pr);
  }
  __syncthreads();
  const int e = tid >> 2, kc = (tid & 3) * 16;
  ushort8 a = *reinterpret_cast<ushort8*>(&t[e][kc]);
  ushort8 b = *reinterpret_cast<ushort8*>(&t[e][kc + 8]);
  unsigned short* dst = (unsigned short*)w3t + (size_t)(e0 + e) * KD + k0 + kc;
  *reinterpret_cast<ushort8*>(dst) = a;
  *reinterpret_cast<ushort8*>(dst + 8) = b;
}

// ---------------- in-place row softmax over bf16 logits [M rows x 4096] ----------------
__global__ __launch_bounds__(256) void softmax_rows(unsigned short* __restrict__ S) {
  const int K = 4096;
  unsigned short* row = S + (size_t)blockIdx.x * K;
  const int tid = threadIdx.x;
  const int lane = tid & 63, w = tid >> 6;
  __shared__ float red[8];

  ushort8 v0 = *reinterpret_cast<const ushort8*>(row + tid * 8);
  ushort8 v1 = *reinterpret_cast<const ushort8*>(row + 2048 + tid * 8);
  float x[16];
#pragma unroll
  for (int i = 0; i < 8; ++i) {
    x[i]     = __uint_as_float(((unsigned)v0[i]) << 16);
    x[8 + i] = __uint_as_float(((unsigned)v1[i]) << 16);
  }
  float mx = x[0];
#pragma unroll
  for (int i = 1; i < 16; ++i) mx = fmaxf(mx, x[i]);
#pragma unroll
  for (int o = 32; o; o >>= 1) mx = fmaxf(mx, __shfl_xor(mx, o));
  if (lane == 0) red[w] = mx;
  __syncthreads();
  mx = fmaxf(fmaxf(red[0], red[1]), fmaxf(red[2], red[3]));

  float s = 0.f;
#pragma unroll
  for (int i = 0; i < 16; ++i) { x[i] = __expf(x[i] - mx); s += x[i]; }
#pragma unroll
  for (int o = 32; o; o >>= 1) s += __shfl_xor(s, o);
  if (lane == 0) red[4 + w] = s;
  __syncthreads();
  const float inv = 1.f / (red[4] + red[5] + red[6] + red[7]);

  ushort8 o0, o1;
#pragma unroll
  for (int i = 0; i < 8; ++i) {
    bf16 b0 = (bf16)(x[i] * inv);
    bf16 b1 = (bf16)(x[8 + i] * inv);
    o0[i] = __builtin_bit_cast(unsigned short, b0);
    o1[i] = __builtin_bit_cast(unsigned short, b1);
  }
  *reinterpret_cast<ushort8*>(row + tid * 8) = o0;
  *reinterpret_cast<ushort8*>(row + 2048 + tid * 8) = o1;
}

extern "C" void kernel_launch(void* const* d_in, const int* in_sizes, int n_in,
                              void* d_out, int out_size, void* d_ws, size_t ws_size,
                              hipStream_t stream) {
  const float* y     = (const float*)d_in[0];  // [16384,1024]
  const float* Wy_w  = (const float*)d_in[1];  // [1024,1024]
  const float* Wy_b  = (const float*)d_in[2];  // [1024]
  const float* Wz_w  = (const float*)d_in[3];  // [1024,2048]
  const float* Wz_b  = (const float*)d_in[4];  // [1024]
  const float* dic   = (const float*)d_in[5];  // [4096,2048]
  const float* prior = (const float*)d_in[6];  // [4096]
  float* z = (float*)d_out;                    // [16384,2048]

  const int M = 16384, D = 1024, E = 2048, KD = 4096;

  // workspace (184 MiB, same footprint as verified round 1):
  //  w3t @0 (16M) | h @16M (32M) | dz @48M (8M) | S @56M (128M)
  //  cast buffers overlaid INSIDE S (dead before S is written):
  //  yb @56M (32M) | Wyb @88M (2M) | Wzb @90M (4M) | dicb @94M (16M)
  char* ws = (char*)d_ws;
  bf16* w3t  = (bf16*)(ws);
  bf16* h    = (bf16*)(ws + ((size_t)16 << 20));
  bf16* dzb  = (bf16*)(ws + ((size_t)48 << 20));
  bf16* S    = (bf16*)(ws + ((size_t)56 << 20));
  bf16* yb   = (bf16*)(ws + ((size_t)56 << 20));
  bf16* Wyb  = (bf16*)(ws + ((size_t)88 << 20));
  bf16* Wzb  = (bf16*)(ws + ((size_t)90 << 20));
  bf16* dicb = (bf16*)(ws + ((size_t)94 << 20));

  // 0) pre-cast all f32 GEMM operands to bf16 (vectorized, memory-bound)
  cast_bf16<<<2048, 256, 0, stream>>>(y, yb, M * D / 8);
  cast_bf16<<<512, 256, 0, stream>>>(Wy_w, Wyb, D * D / 8);
  cast_bf16<<<512, 256, 0, stream>>>(Wz_w, Wzb, D * E / 8);
  cast_bf16<<<1024, 256, 0, stream>>>(dic, dicb, KD * E / 8);
  // 1) W3t[e,k] = prior[k] * dic_z[k,e]
  prep_w3t<<<dim3(KD / 64, E / 64), 256, 0, stream>>>(dic, prior, w3t);
  // 2) h = yb . Wyb^T + Wy_b   -> bf16 [16384,1024]
  gemm_nt_bf16<true, true><<<dim3(M / 128, D / 128), 256, 0, stream>>>(
      yb, Wyb, Wy_b, h, M, D, D, 1.0f);
  // 3) dz = dicb . Wzb^T + Wz_b -> bf16 [4096,1024]
  gemm_nt_bf16<true, true><<<dim3(KD / 128, D / 128), 256, 0, stream>>>(
      dicb, Wzb, Wz_b, dzb, KD, D, E, 1.0f);
  // 4) S = (h . dz^T) / 32      -> bf16 [16384,4096]  (overwrites cast buffers)
  gemm_nt_bf16<true, false><<<dim3(M / 128, KD / 128), 256, 0, stream>>>(
      h, dzb, nullptr, S, M, KD, D, 0.03125f);
  // 5) row softmax in place
  softmax_rows<<<M, 256, 0, stream>>>((unsigned short*)S);
  // 6) z = att . w3t^T          -> f32 [16384,2048]
  gemm_nt_bf16<false, false><<<dim3(M / 128, E / 128), 256, 0, stream>>>(
      S, w3t, nullptr, z, M, E, KD, 1.0f);
}

// Round 3
// 697.388 us; speedup vs baseline: 1.1631x; 1.0536x over previous
//
#include <hip/hip_runtime.h>
#include <hip/hip_bf16.h>
#include <stdint.h>

typedef __bf16 bf16;
typedef __bf16 bf16x4 __attribute__((ext_vector_type(4)));
typedef __bf16 bf16x8 __attribute__((ext_vector_type(8)));
typedef float f32x4 __attribute__((ext_vector_type(4)));
typedef unsigned short ushort8 __attribute__((ext_vector_type(8)));

// ---- async global->LDS, 16B per lane. LDS dest wave-uniform base; HW adds lane*16.
__device__ __forceinline__ void gload16(const bf16* g, bf16* l) {
  __builtin_amdgcn_global_load_lds(
      reinterpret_cast<const __attribute__((address_space(1))) unsigned int*>(
          reinterpret_cast<uintptr_t>(g)),
      reinterpret_cast<__attribute__((address_space(3))) unsigned int*>(
          reinterpret_cast<uintptr_t>(l)),
      16, 0, 0);
}

// ---- f32 -> bf16 cast, 8 elems/thread, grid-stride ----
__global__ __launch_bounds__(256) void cast_bf16(const float* __restrict__ in,
                                                 bf16* __restrict__ out, int n8) {
  int i = blockIdx.x * blockDim.x + threadIdx.x;
  const int stride = gridDim.x * blockDim.x;
  for (; i < n8; i += stride) {
    const float4 v0 = reinterpret_cast<const float4*>(in)[i * 2];
    const float4 v1 = reinterpret_cast<const float4*>(in)[i * 2 + 1];
    bf16x8 o = { (bf16)v0.x, (bf16)v0.y, (bf16)v0.z, (bf16)v0.w,
                 (bf16)v1.x, (bf16)v1.y, (bf16)v1.z, (bf16)v1.w };
    reinterpret_cast<bf16x8*>(out)[i] = o;
  }
}

// ================= 8-phase-style pipelined NT GEMM =================
// C[M,N] = scale*(A[M,K].B[N,K]^T)+bias.  Tile 256x128, BK=64, 512 thr = 8 waves
// (4M x 2N, wave C = 64x64).  3 LDS slots (48KB: A 256x64, B 128x64) round-robin;
// group g computes T(g) from slot g%3 while staging T(g+2) into slot (g+2)%3
// (held T(g-1), consumed last group -> provably race-free).  vmcnt(6) once per
// group proves T(g+1) landed.  LDS XOR-swizzle slot^=(row&7) on both sides.
#define STA(PD, KQ, U) gload16(gA + (size_t)(U) * 64 * K + (KQ), (bf16*)((PD) + (U) * 8192 + w * 1024))
#define STB(PD, KQ, U) gload16(gB + (size_t)(U) * 64 * K + (KQ), (bf16*)((PD) + (U) * 8192 + w * 1024))

#define PHASE(SA, SB, QM, STAGES, ENDWAIT) do {                               \
    bf16x8 af[2][2], bb[4][2];                                                \
    _Pragma("unroll")                                                         \
    for (int mi = 0; mi < 2; ++mi) {                                          \
      af[mi][0] = *(const bf16x8*)((SA) + ((QM) * 32 + mi * 16) * 128 + aoff0); \
      af[mi][1] = *(const bf16x8*)((SA) + ((QM) * 32 + mi * 16) * 128 + aoff1); \
    }                                                                         \
    _Pragma("unroll")                                                         \
    for (int ni = 0; ni < 4; ++ni) {                                          \
      bb[ni][0] = *(const bf16x8*)((SB) + ni * 2048 + aoff0);                 \
      bb[ni][1] = *(const bf16x8*)((SB) + ni * 2048 + aoff1);                 \
    }                                                                         \
    STAGES;                                                                   \
    __builtin_amdgcn_s_barrier();                                             \
    __builtin_amdgcn_s_setprio(1);                                            \
    _Pragma("unroll")                                                         \
    for (int ni = 0; ni < 4; ++ni)                                            \
      _Pragma("unroll")                                                       \
      for (int mi = 0; mi < 2; ++mi) {                                        \
        acc[(QM) * 2 + mi][ni] = __builtin_amdgcn_mfma_f32_16x16x32_bf16(     \
            af[mi][0], bb[ni][0], acc[(QM) * 2 + mi][ni], 0, 0, 0);           \
        acc[(QM) * 2 + mi][ni] = __builtin_amdgcn_mfma_f32_16x16x32_bf16(     \
            af[mi][1], bb[ni][1], acc[(QM) * 2 + mi][ni], 0, 0, 0);           \
      }                                                                       \
    __builtin_amdgcn_s_setprio(0);                                            \
    ENDWAIT;                                                                  \
    __builtin_amdgcn_s_barrier();                                             \
  } while (0)

template <bool OUT_BF16, bool HAS_BIAS>
__global__ __launch_bounds__(512, 2) void gemm8p(
    const bf16* __restrict__ A, const bf16* __restrict__ B,
    const float* __restrict__ bias, void* __restrict__ Cout,
    int M, int N, int K, float scale) {
  extern __shared__ char lds[];
  const int tid = threadIdx.x;
  const int lane = tid & 63, w = tid >> 6;

  // T1: bijective XCD swizzle on linearized block id (m204 formula)
  const int nwg = gridDim.x * gridDim.y;
  const int orig = blockIdx.y * gridDim.x + blockIdx.x;
  int wgid;
  { const int q = nwg >> 3, r = nwg & 7, x = orig & 7, rest = orig >> 3;
    wgid = (x < r ? x * (q + 1) : r * (q + 1) + (x - r) * q) + rest; }
  const int m0 = (wgid % gridDim.x) * 256;
  const int n0 = (wgid / gridDim.x) * 128;

  // staging source (pre-swizzled global col so linear LDS dest holds swizzled data)
  const int srow = lane >> 3;                     // 0..7
  const int scol = ((lane & 7) ^ srow) * 8;       // slot XOR row&7
  const bf16* gA = A + (size_t)(m0 + w * 8 + srow) * K + scol;
  const bf16* gB = B + (size_t)(n0 + w * 8 + srow) * K + scol;

  // fragment read offsets (swizzled): row*128 + ((kk*4+hi)^(row&7))*16
  const int fr = lane & 15, hi = lane >> 4;
  const int aoff0 = fr * 128 + ((hi ^ (lane & 7)) * 16);
  const int aoff1 = aoff0 ^ 64;
  const int wr = w >> 1, wc = w & 1;              // 4M x 2N waves

  f32x4 acc[4][4] = {};
  const int NT = K >> 6;

  // prologue: stage T0 -> slot0, T1 -> slot1 (12 loads), wait T0 (vmcnt(6))
  {
    char* P0 = lds;            char* Q0 = lds + 32768;
    char* P1 = lds + 49152;    char* Q1 = P1 + 32768;
    STA(P0, 0, 0); STA(P0, 0, 1); STA(P0, 0, 2); STA(P0, 0, 3);
    STB(Q0, 0, 0); STB(Q0, 0, 1);
    STA(P1, 64, 0); STA(P1, 64, 1); STA(P1, 64, 2); STA(P1, 64, 3);
    STB(Q1, 64, 0); STB(Q1, 64, 1);
  }
  asm volatile("s_waitcnt vmcnt(6)" ::: "memory");
  __builtin_amdgcn_s_barrier();

  for (int t = 0; t < NT; ++t) {
    const int s = t % 3, sp = (t + 2) % 3;
    const char* SA = lds + s * 49152 + wr * 8192;
    const char* SB = lds + s * 49152 + 32768 + wc * 8192;
    char* PA = lds + sp * 49152;
    char* PB = PA + 32768;
    const bool st = (t + 2) < NT;
    const size_t kq = (size_t)(t + 2) * 64;
    PHASE(SA, SB, 0,
          { if (st) { STA(PA, kq, 0); STA(PA, kq, 1); STA(PA, kq, 2); } },
          {});
    PHASE(SA, SB, 1,
          { if (st) { STA(PA, kq, 3); STB(PB, kq, 0); STB(PB, kq, 1); } },
          { if (st) { asm volatile("s_waitcnt vmcnt(6)" ::: "memory"); }
            else    { asm volatile("s_waitcnt vmcnt(0)" ::: "memory"); } });
  }

  // epilogue: C/D layout col = lane&15, row = (lane>>4)*4 + j  [m89-verified]
  const int lro = hi * 4;
#pragma unroll
  for (int ni = 0; ni < 4; ++ni) {
    const int gcol = n0 + wc * 64 + ni * 16 + fr;
    float bvs = 0.f;
    if constexpr (HAS_BIAS) bvs = bias[gcol];
#pragma unroll
    for (int mi = 0; mi < 4; ++mi) {
      const int grow = m0 + wr * 64 + mi * 16 + lro;
#pragma unroll
      for (int j = 0; j < 4; ++j) {
        const float c = acc[mi][ni][j] * scale + bvs;
        if constexpr (OUT_BF16)
          ((bf16*)Cout)[(size_t)(grow + j) * N + gcol] = (bf16)c;
        else
          ((float*)Cout)[(size_t)(grow + j) * N + gcol] = c;
      }
    }
  }
}

// ---------------- prep: W3t[e,k] = bf16(prior[k] * dic_z[k,e]), transposed ----------------
__global__ __launch_bounds__(256) void prep_w3t(const float* __restrict__ dic,
                                                const float* __restrict__ prior,
                                                bf16* __restrict__ w3t) {
  const int KD = 4096, E = 2048;
  __shared__ bf16 t[64][72];
  const int k0 = blockIdx.x * 64, e0 = blockIdx.y * 64;
  const int tid = threadIdx.x;
  const int er = (tid & 15) * 4;
  const int kr = tid >> 4;
#pragma unroll
  for (int p = 0; p < 4; ++p) {
    const int k = kr + p * 16;
    const float pr = prior[k0 + k];
    const float4 v = *reinterpret_cast<const float4*>(dic + (size_t)(k0 + k) * E + e0 + er);
    t[er + 0][k] = (bf16)(v.x * pr);
    t[er + 1][k] = (bf16)(v.y * pr);
    t[er + 2][k] = (bf16)(v.z * pr);
    t[er + 3][k] = (bf16)(v.w * pr);
  }
  __syncthreads();
  const int e = tid >> 2, kc = (tid & 3) * 16;
  ushort8 a = *reinterpret_cast<ushort8*>(&t[e][kc]);
  ushort8 b = *reinterpret_cast<ushort8*>(&t[e][kc + 8]);
  unsigned short* dst = (unsigned short*)w3t + (size_t)(e0 + e) * KD + k0 + kc;
  *reinterpret_cast<ushort8*>(dst) = a;
  *reinterpret_cast<ushort8*>(dst + 8) = b;
}

// ---------------- in-place row softmax over bf16 logits [M rows x 4096] ----------------
__global__ __launch_bounds__(256) void softmax_rows(unsigned short* __restrict__ S) {
  const int K = 4096;
  unsigned short* row = S + (size_t)blockIdx.x * K;
  const int tid = threadIdx.x;
  const int lane = tid & 63, w = tid >> 6;
  __shared__ float red[8];

  ushort8 v0 = *reinterpret_cast<const ushort8*>(row + tid * 8);
  ushort8 v1 = *reinterpret_cast<const ushort8*>(row + 2048 + tid * 8);
  float x[16];
#pragma unroll
  for (int i = 0; i < 8; ++i) {
    x[i]     = __uint_as_float(((unsigned)v0[i]) << 16);
    x[8 + i] = __uint_as_float(((unsigned)v1[i]) << 16);
  }
  float mx = x[0];
#pragma unroll
  for (int i = 1; i < 16; ++i) mx = fmaxf(mx, x[i]);
#pragma unroll
  for (int o = 32; o; o >>= 1) mx = fmaxf(mx, __shfl_xor(mx, o));
  if (lane == 0) red[w] = mx;
  __syncthreads();
  mx = fmaxf(fmaxf(red[0], red[1]), fmaxf(red[2], red[3]));

  float s = 0.f;
#pragma unroll
  for (int i = 0; i < 16; ++i) { x[i] = __expf(x[i] - mx); s += x[i]; }
#pragma unroll
  for (int o = 32; o; o >>= 1) s += __shfl_xor(s, o);
  if (lane == 0) red[4 + w] = s;
  __syncthreads();
  const float inv = 1.f / (red[4] + red[5] + red[6] + red[7]);

  ushort8 o0, o1;
#pragma unroll
  for (int i = 0; i < 8; ++i) {
    bf16 b0 = (bf16)(x[i] * inv);
    bf16 b1 = (bf16)(x[8 + i] * inv);
    o0[i] = __builtin_bit_cast(unsigned short, b0);
    o1[i] = __builtin_bit_cast(unsigned short, b1);
  }
  *reinterpret_cast<ushort8*>(row + tid * 8) = o0;
  *reinterpret_cast<ushort8*>(row + 2048 + tid * 8) = o1;
}

extern "C" void kernel_launch(void* const* d_in, const int* in_sizes, int n_in,
                              void* d_out, int out_size, void* d_ws, size_t ws_size,
                              hipStream_t stream) {
  const float* y     = (const float*)d_in[0];  // [16384,1024]
  const float* Wy_w  = (const float*)d_in[1];  // [1024,1024]
  const float* Wy_b  = (const float*)d_in[2];  // [1024]
  const float* Wz_w  = (const float*)d_in[3];  // [1024,2048]
  const float* Wz_b  = (const float*)d_in[4];  // [1024]
  const float* dic   = (const float*)d_in[5];  // [4096,2048]
  const float* prior = (const float*)d_in[6];  // [4096]
  float* z = (float*)d_out;                    // [16384,2048]

  const int M = 16384, D = 1024, E = 2048, KD = 4096;
  const size_t LDSB = 147456;  // 3 slots x 48KB

  char* ws = (char*)d_ws;
  bf16* w3t  = (bf16*)(ws);
  bf16* h    = (bf16*)(ws + ((size_t)16 << 20));
  bf16* dzb  = (bf16*)(ws + ((size_t)48 << 20));
  bf16* S    = (bf16*)(ws + ((size_t)56 << 20));
  bf16* yb   = (bf16*)(ws + ((size_t)56 << 20));
  bf16* Wyb  = (bf16*)(ws + ((size_t)88 << 20));
  bf16* Wzb  = (bf16*)(ws + ((size_t)90 << 20));
  bf16* dicb = (bf16*)(ws + ((size_t)94 << 20));

  // 0) pre-cast f32 operands to bf16
  cast_bf16<<<2048, 256, 0, stream>>>(y, yb, M * D / 8);
  cast_bf16<<<512, 256, 0, stream>>>(Wy_w, Wyb, D * D / 8);
  cast_bf16<<<512, 256, 0, stream>>>(Wz_w, Wzb, D * E / 8);
  cast_bf16<<<1024, 256, 0, stream>>>(dic, dicb, KD * E / 8);
  // 1) W3t[e,k] = prior[k] * dic_z[k,e]
  prep_w3t<<<dim3(KD / 64, E / 64), 256, 0, stream>>>(dic, prior, w3t);
  // 2) h = yb . Wyb^T + Wy_b   -> bf16 [16384,1024]
  gemm8p<true, true><<<dim3(M / 256, D / 128), 512, LDSB, stream>>>(
      yb, Wyb, Wy_b, h, M, D, D, 1.0f);
  // 3) dz = dicb . Wzb^T + Wz_b -> bf16 [4096,1024]
  gemm8p<true, true><<<dim3(KD / 256, D / 128), 512, LDSB, stream>>>(
      dicb, Wzb, Wz_b, dzb, KD, D, E, 1.0f);
  // 4) S = (h . dz^T) / 32      -> bf16 [16384,4096]
  gemm8p<true, false><<<dim3(M / 256, KD / 128), 512, LDSB, stream>>>(
      h, dzb, nullptr, S, M, KD, D, 0.03125f);
  // 5) row softmax in place
  softmax_rows<<<M, 256, 0, stream>>>((unsigned short*)S);
  // 6) z = att . w3t^T          -> f32 [16384,2048]
  gemm8p<false, false><<<dim3(M / 256, E / 128), 512, LDSB, stream>>>(
      S, w3t, nullptr, z, M, E, KD, 1.0f);
}

// Round 4
// 577.016 us; speedup vs baseline: 1.4057x; 1.2086x over previous
//
#include <hip/hip_runtime.h>
#include <hip/hip_bf16.h>
#include <stdint.h>

typedef __bf16 bf16;
typedef __bf16 bf16x4 __attribute__((ext_vector_type(4)));
typedef __bf16 bf16x8 __attribute__((ext_vector_type(8)));
typedef float f32x4 __attribute__((ext_vector_type(4)));
typedef unsigned short ushort8 __attribute__((ext_vector_type(8)));

// ---- async global->LDS, 16B per lane. LDS dest wave-uniform base; HW adds lane*16.
__device__ __forceinline__ void gload16(const bf16* g, char* l) {
  __builtin_amdgcn_global_load_lds(
      reinterpret_cast<const __attribute__((address_space(1))) unsigned int*>(
          reinterpret_cast<uintptr_t>(g)),
      reinterpret_cast<__attribute__((address_space(3))) unsigned int*>(
          reinterpret_cast<uintptr_t>(l)),
      16, 0, 0);
}

// ---- f32 -> bf16 cast, 8 elems/thread, grid-stride ----
__global__ __launch_bounds__(256) void cast_bf16(const float* __restrict__ in,
                                                 bf16* __restrict__ out, int n8) {
  int i = blockIdx.x * blockDim.x + threadIdx.x;
  const int stride = gridDim.x * blockDim.x;
  for (; i < n8; i += stride) {
    const float4 v0 = reinterpret_cast<const float4*>(in)[i * 2];
    const float4 v1 = reinterpret_cast<const float4*>(in)[i * 2 + 1];
    bf16x8 o = { (bf16)v0.x, (bf16)v0.y, (bf16)v0.z, (bf16)v0.w,
                 (bf16)v1.x, (bf16)v1.y, (bf16)v1.z, (bf16)v1.w };
    reinterpret_cast<bf16x8*>(out)[i] = o;
  }
}

// ================= deep-pipelined NT GEMM =================
// C[M,N] = scale*(A[M,K].B[N,K]^T)+bias.  BM=256, BK=32, 512 thr = 8 waves.
// BN=256: waves 2M x 4N (wave-tile 128x64, 32 MFMA/tile); BN=128: 4M x 2N (64x64).
// 4 LDS slots (A[256][32] + B[BN][32] bf16); tile t computes from slot t&3 while
// staging t+3 into slot (t+3)&3 (last read at t-1, reads completed pre-barrier ->
// race-free).  vmcnt(2L) at tile end proves t+1 landed (L = gloads/wave/tile).
// Swizzle: 16B-slot ^= (row>>1)&3, both sides (pre-swizzled global src + read).
template <bool OUT_BF16, bool HAS_BIAS, int BN>
__global__ __launch_bounds__(512, 2) void gemm_pipe(
    const bf16* __restrict__ A, const bf16* __restrict__ B,
    const float* __restrict__ bias, void* __restrict__ Cout,
    int M, int N, int K, float scale) {
  constexpr int BM = 256;
  constexpr int SLOT = (BM + BN) * 64;           // bytes per slot
  constexpr int BOFF = BM * 64;                  // B region offset in slot
  constexpr int TM = (BN == 256) ? 128 : 64;     // wave-tile M
  constexpr int MI = TM / 16;                    // 8 or 4
  constexpr int NI = 4;                          // wave-tile N = 64
  extern __shared__ char lds[];
  const int tid = threadIdx.x;
  const int lane = tid & 63, w = tid >> 6;

  // block mapping: bijective XCD chunking (m204), n-fast within chunk (L2 A-reuse)
  const int gridN = N / BN;
  const int nwg = gridDim.x;
  const int orig = blockIdx.x;
  int wgid;
  { const int q = nwg >> 3, r = nwg & 7, x = orig & 7, rest = orig >> 3;
    wgid = (x < r ? x * (q + 1) : r * (q + 1) + (x - r) * q) + rest; }
  const int m0 = (wgid / gridN) * BM;
  const int n0 = (wgid % gridN) * BN;

  // ---- staging source (pre-swizzled global col so linear LDS dest = swizzled) ----
  const int srow = w * 16 + (lane >> 2);               // 0..127
  const int scol = (((lane & 3) ^ ((srow >> 1) & 3))) * 8;
  const bf16* gA  = A + (size_t)(m0 + srow) * K + scol;
  const bf16* gA2 = gA + (size_t)128 * K;
  const bf16* gB  = B + (size_t)(n0 + srow) * K + scol;
  const bf16* gB2 = (BN == 256) ? gB + (size_t)128 * K : gB;

  auto stage = [&](int T) {
    char* sb = lds + (size_t)(T & 3) * SLOT;
    const int kc = T * 32;
    gload16(gA + kc,  sb + w * 1024);
    gload16(gA2 + kc, sb + 8192 + w * 1024);
    gload16(gB + kc,  sb + BOFF + w * 1024);
    if constexpr (BN == 256) gload16(gB2 + kc, sb + BOFF + 8192 + w * 1024);
  };

  // ---- fragment read offsets (swizzled) ----
  const int fr = lane & 15, hi = lane >> 4;
  int wm, wn;
  if constexpr (BN == 256) { wm = w >> 2; wn = w & 3; }
  else                     { wm = w >> 1; wn = w & 1; }
  int aoff[MI], boff[NI];
#pragma unroll
  for (int mi = 0; mi < MI; ++mi) {
    const int row = wm * TM + mi * 16 + fr;
    aoff[mi] = row * 64 + ((hi ^ ((row >> 1) & 3)) << 4);
  }
#pragma unroll
  for (int ni = 0; ni < NI; ++ni) {
    const int row = wn * 64 + ni * 16 + fr;
    boff[ni] = BOFF + row * 64 + ((hi ^ ((row >> 1) & 3)) << 4);
  }

  f32x4 acc[MI][NI] = {};
  const int NT = K >> 5;

  // prologue: stage tiles 0,1,2 (3L loads in flight), prove tile 0 (vmcnt(2L))
  stage(0); stage(1); stage(2);
  if constexpr (BN == 256) asm volatile("s_waitcnt vmcnt(8)" ::: "memory");
  else                     asm volatile("s_waitcnt vmcnt(6)" ::: "memory");
  __builtin_amdgcn_s_barrier();

  for (int t = 0; t < NT; ++t) {
    const char* sb = lds + (size_t)(t & 3) * SLOT;
    bf16x8 af[MI], bb[NI];
#pragma unroll
    for (int mi = 0; mi < MI; ++mi) af[mi] = *reinterpret_cast<const bf16x8*>(sb + aoff[mi]);
#pragma unroll
    for (int ni = 0; ni < NI; ++ni) bb[ni] = *reinterpret_cast<const bf16x8*>(sb + boff[ni]);
    if (t + 3 < NT) stage(t + 3);
    __builtin_amdgcn_s_barrier();
    __builtin_amdgcn_s_setprio(1);
#pragma unroll
    for (int mi = 0; mi < MI; ++mi)
#pragma unroll
      for (int ni = 0; ni < NI; ++ni)
        acc[mi][ni] = __builtin_amdgcn_mfma_f32_16x16x32_bf16(af[mi], bb[ni], acc[mi][ni], 0, 0, 0);
    __builtin_amdgcn_s_setprio(0);
    if (t + 3 < NT) {
      if constexpr (BN == 256) asm volatile("s_waitcnt vmcnt(8)" ::: "memory");
      else                     asm volatile("s_waitcnt vmcnt(6)" ::: "memory");
    } else if (t + 2 < NT) {
      if constexpr (BN == 256) asm volatile("s_waitcnt vmcnt(4)" ::: "memory");
      else                     asm volatile("s_waitcnt vmcnt(3)" ::: "memory");
    } else if (t + 1 < NT) {
      asm volatile("s_waitcnt vmcnt(0)" ::: "memory");
    }
    __builtin_amdgcn_s_barrier();
  }

  // epilogue: C/D layout col = lane&15, row = (lane>>4)*4 + j  [m89-verified]
  const int lro = hi * 4;
#pragma unroll
  for (int ni = 0; ni < NI; ++ni) {
    const int gcol = n0 + wn * 64 + ni * 16 + fr;
    float bvs = 0.f;
    if constexpr (HAS_BIAS) bvs = bias[gcol];
#pragma unroll
    for (int mi = 0; mi < MI; ++mi) {
      const int grow = m0 + wm * TM + mi * 16 + lro;
#pragma unroll
      for (int j = 0; j < 4; ++j) {
        const float c = acc[mi][ni][j] * scale + bvs;
        if constexpr (OUT_BF16)
          ((bf16*)Cout)[(size_t)(grow + j) * N + gcol] = (bf16)c;
        else
          ((float*)Cout)[(size_t)(grow + j) * N + gcol] = c;
      }
    }
  }
}

// ---------------- prep: W3t[e,k] = bf16(prior[k] * dic_z[k,e]), transposed ----------------
__global__ __launch_bounds__(256) void prep_w3t(const float* __restrict__ dic,
                                                const float* __restrict__ prior,
                                                bf16* __restrict__ w3t) {
  const int KD = 4096, E = 2048;
  __shared__ bf16 t[64][72];
  const int k0 = blockIdx.x * 64, e0 = blockIdx.y * 64;
  const int tid = threadIdx.x;
  const int er = (tid & 15) * 4;
  const int kr = tid >> 4;
#pragma unroll
  for (int p = 0; p < 4; ++p) {
    const int k = kr + p * 16;
    const float pr = prior[k0 + k];
    const float4 v = *reinterpret_cast<const float4*>(dic + (size_t)(k0 + k) * E + e0 + er);
    t[er + 0][k] = (bf16)(v.x * pr);
    t[er + 1][k] = (bf16)(v.y * pr);
    t[er + 2][k] = (bf16)(v.z * pr);
    t[er + 3][k] = (bf16)(v.w * pr);
  }
  __syncthreads();
  const int e = tid >> 2, kc = (tid & 3) * 16;
  ushort8 a = *reinterpret_cast<ushort8*>(&t[e][kc]);
  ushort8 b = *reinterpret_cast<ushort8*>(&t[e][kc + 8]);
  unsigned short* dst = (unsigned short*)w3t + (size_t)(e0 + e) * KD + k0 + kc;
  *reinterpret_cast<ushort8*>(dst) = a;
  *reinterpret_cast<ushort8*>(dst + 8) = b;
}

// ---------------- in-place row softmax over bf16 logits [M rows x 4096] ----------------
__global__ __launch_bounds__(256) void softmax_rows(unsigned short* __restrict__ S) {
  const int K = 4096;
  unsigned short* row = S + (size_t)blockIdx.x * K;
  const int tid = threadIdx.x;
  const int lane = tid & 63, w = tid >> 6;
  __shared__ float red[8];

  ushort8 v0 = *reinterpret_cast<const ushort8*>(row + tid * 8);
  ushort8 v1 = *reinterpret_cast<const ushort8*>(row + 2048 + tid * 8);
  float x[16];
#pragma unroll
  for (int i = 0; i < 8; ++i) {
    x[i]     = __uint_as_float(((unsigned)v0[i]) << 16);
    x[8 + i] = __uint_as_float(((unsigned)v1[i]) << 16);
  }
  float mx = x[0];
#pragma unroll
  for (int i = 1; i < 16; ++i) mx = fmaxf(mx, x[i]);
#pragma unroll
  for (int o = 32; o; o >>= 1) mx = fmaxf(mx, __shfl_xor(mx, o));
  if (lane == 0) red[w] = mx;
  __syncthreads();
  mx = fmaxf(fmaxf(red[0], red[1]), fmaxf(red[2], red[3]));

  float s = 0.f;
#pragma unroll
  for (int i = 0; i < 16; ++i) { x[i] = __expf(x[i] - mx); s += x[i]; }
#pragma unroll
  for (int o = 32; o; o >>= 1) s += __shfl_xor(s, o);
  if (lane == 0) red[4 + w] = s;
  __syncthreads();
  const float inv = 1.f / (red[4] + red[5] + red[6] + red[7]);

  ushort8 o0, o1;
#pragma unroll
  for (int i = 0; i < 8; ++i) {
    bf16 b0 = (bf16)(x[i] * inv);
    bf16 b1 = (bf16)(x[8 + i] * inv);
    o0[i] = __builtin_bit_cast(unsigned short, b0);
    o1[i] = __builtin_bit_cast(unsigned short, b1);
  }
  *reinterpret_cast<ushort8*>(row + tid * 8) = o0;
  *reinterpret_cast<ushort8*>(row + 2048 + tid * 8) = o1;
}

extern "C" void kernel_launch(void* const* d_in, const int* in_sizes, int n_in,
                              void* d_out, int out_size, void* d_ws, size_t ws_size,
                              hipStream_t stream) {
  const float* y     = (const float*)d_in[0];  // [16384,1024]
  const float* Wy_w  = (const float*)d_in[1];  // [1024,1024]
  const float* Wy_b  = (const float*)d_in[2];  // [1024]
  const float* Wz_w  = (const float*)d_in[3];  // [1024,2048]
  const float* Wz_b  = (const float*)d_in[4];  // [1024]
  const float* dic   = (const float*)d_in[5];  // [4096,2048]
  const float* prior = (const float*)d_in[6];  // [4096]
  float* z = (float*)d_out;                    // [16384,2048]

  const int M = 16384, D = 1024, E = 2048, KD = 4096;

  char* ws = (char*)d_ws;
  bf16* w3t  = (bf16*)(ws);
  bf16* h    = (bf16*)(ws + ((size_t)16 << 20));
  bf16* dzb  = (bf16*)(ws + ((size_t)48 << 20));
  bf16* S    = (bf16*)(ws + ((size_t)56 << 20));
  bf16* yb   = (bf16*)(ws + ((size_t)56 << 20));
  bf16* Wyb  = (bf16*)(ws + ((size_t)88 << 20));
  bf16* Wzb  = (bf16*)(ws + ((size_t)90 << 20));
  bf16* dicb = (bf16*)(ws + ((size_t)94 << 20));

  // 0) pre-cast f32 operands to bf16
  cast_bf16<<<2048, 256, 0, stream>>>(y, yb, M * D / 8);
  cast_bf16<<<512, 256, 0, stream>>>(Wy_w, Wyb, D * D / 8);
  cast_bf16<<<512, 256, 0, stream>>>(Wz_w, Wzb, D * E / 8);
  cast_bf16<<<1024, 256, 0, stream>>>(dic, dicb, KD * E / 8);
  // 1) W3t[e,k] = prior[k] * dic_z[k,e]
  prep_w3t<<<dim3(KD / 64, E / 64), 256, 0, stream>>>(dic, prior, w3t);
  // 2) h = yb . Wyb^T + Wy_b   -> bf16 [16384,1024]   grid 64x4 = 256
  gemm_pipe<true, true, 256><<<(M / 256) * (D / 256), 512, 131072, stream>>>(
      yb, Wyb, Wy_b, h, M, D, D, 1.0f);
  // 3) dz = dicb . Wzb^T + Wz_b -> bf16 [4096,1024]   grid 16x8 = 128
  gemm_pipe<true, true, 128><<<(KD / 256) * (D / 128), 512, 98304, stream>>>(
      dicb, Wzb, Wz_b, dzb, KD, D, E, 1.0f);
  // 4) S = (h . dz^T) / 32      -> bf16 [16384,4096]  grid 64x16 = 1024
  gemm_pipe<true, false, 256><<<(M / 256) * (KD / 256), 512, 131072, stream>>>(
      h, dzb, nullptr, S, M, KD, D, 0.03125f);
  // 5) row softmax in place
  softmax_rows<<<M, 256, 0, stream>>>((unsigned short*)S);
  // 6) z = att . w3t^T          -> f32 [16384,2048]   grid 64x8 = 512
  gemm_pipe<false, false, 256><<<(M / 256) * (E / 256), 512, 131072, stream>>>(
      S, w3t, nullptr, z, M, E, KD, 1.0f);
}